// Round 7
// baseline (194.428 us; speedup 1.0000x reference)
//
#include <hip/hip_runtime.h>
#include <stdint.h>
#include <math.h>

// RNG (jax.random.uniform(key(42), (16384,256,4), f32)), modern default
// jax_threefry_partitionable=True, per jax/_src/prng.py
// _threefry_random_bits_partitionable:
//   counts1, counts2 = iota_2x32_shape(shape)   # hi/lo words of 64-bit iota
//   bits1, bits2 = threefry2x32(k1=0, k2=42, c0=counts1=0, c1=counts2=i)
//   bit_width==32  ->  bits[i] = bits1 ^ bits2      <-- XOR of BOTH words
// u = bitcast((bits>>9)|0x3F800000) - 1.0f  (exact in f32)
// Eliminated by experiment: legacy halves-split (absmax .7606, R1-R3),
// partitionable word x1 (.8047, R4-stream), word x0 (.8716, R6).
//
// Forward value of straight-through gumbel-softmax = one-hot of
// argmax_k(logits_k + g_k)  (softmax & /tau are monotone; first-wins ties =
// jnp.argmax).  Monotone transform: equals argmax_k pi_k / w_k with
// pi_k = exp(mean_k - max), w_k = -log(u_k + 1e-20) + 1e-20 > 0.
// Decisions in f64 to match a float64 numpy recompute (harness ref=np).

__device__ __forceinline__ uint32_t rotl32(uint32_t x, int r) {
    return (x << r) | (x >> (32 - r));
}

// returns x0 ^ x1 of threefry2x32(key=[0,42], (c0,c1))
__device__ __forceinline__ uint32_t tf2x32_xor(uint32_t c0, uint32_t c1) {
    const uint32_t ks0 = 0u, ks1 = 42u, ks2 = 0x1BD11BF0u; // 0^42^0x1BD11BDA
    uint32_t x0 = c0 + ks0, x1 = c1 + ks1;
#define TF_R(r) { x0 += x1; x1 = rotl32(x1, r); x1 ^= x0; }
    TF_R(13) TF_R(15) TF_R(26) TF_R(6)
    x0 += ks1; x1 += ks2 + 1u;
    TF_R(17) TF_R(29) TF_R(16) TF_R(24)
    x0 += ks2; x1 += ks0 + 2u;
    TF_R(13) TF_R(15) TF_R(26) TF_R(6)
    x0 += ks0; x1 += ks1 + 3u;
    TF_R(17) TF_R(29) TF_R(16) TF_R(24)
    x0 += ks1; x1 += ks2 + 4u;
    TF_R(13) TF_R(15) TF_R(26) TF_R(6)
    x0 += ks2; x1 += ks0 + 5u;
#undef TF_R
    return x0 ^ x1;
}

__device__ __forceinline__ float bits_to_u(uint32_t b) {
    union { uint32_t u; float f; } cv;
    cv.u = (b >> 9) | 0x3F800000u;   // [1,2), 23 random mantissa bits
    return cv.f - 1.0f;              // [0,1), exact
}

__global__ __launch_bounds__(256) void bayes_kernel(
    const float* __restrict__ A,     // [B,4,S] outcomeA
    const float* __restrict__ Bo,    // [B,4,S] outcomeB
    const float* __restrict__ BEVa,  // [B]
    const float* __restrict__ BEVb,  // [B]
    const int*   __restrict__ kapa,  // [B]
    const float* __restrict__ mean,  // [4]
    float*       __restrict__ out)   // [B]
{
    const int b = blockIdx.x;           // 0..16383
    const int s = threadIdx.x;          // 0..255
    const int kp = kapa[b];             // block-uniform

    int ksel = 0;
    if (s < kp) {                       // masked-out samples never matter
        // unnormalized class weights exp(mean_k - mx) in f64 (argmax-invariant)
        const float m0 = mean[0], m1 = mean[1], m2 = mean[2], m3 = mean[3];
        const float mx = fmaxf(fmaxf(m0, m1), fmaxf(m2, m3));
        double pi[4];
        pi[0] = exp((double)m0 - (double)mx);
        pi[1] = exp((double)m1 - (double)mx);
        pi[2] = exp((double)m2 - (double)mx);
        pi[3] = exp((double)m3 - (double)mx);

        const uint32_t i0 = ((uint32_t)(b * 256 + s)) * 4u;
        double best = -1.0;
#pragma unroll
        for (int k = 0; k < 4; ++k) {
            const uint32_t bits = tf2x32_xor(0u, i0 + (uint32_t)k);
            const double u = (double)bits_to_u(bits);
            const double w = -log(u + 1e-20) + 1e-20;   // > 0
            const double sc = pi[k] / w;
            if (sc > best) { best = sc; ksel = k; }     // first-wins ties
        }
    }

    float av = 0.0f, bv = 0.0f;
    if (s < kp) {
        const int off = (b * 4 + ksel) * 256 + s;
        av = A[off];
        bv = Bo[off];
    }

    // wave (64-lane) reduce, then cross-wave via LDS
#pragma unroll
    for (int off = 32; off >= 1; off >>= 1) {
        av += __shfl_down(av, off);
        bv += __shfl_down(bv, off);
    }

    __shared__ float red[4][2];
    const int wid  = threadIdx.x >> 6;
    const int lane = threadIdx.x & 63;
    if (lane == 0) { red[wid][0] = av; red[wid][1] = bv; }
    __syncthreads();

    if (threadIdx.x == 0) {
        float sA = 0.f, sB = 0.f;
#pragma unroll
        for (int w = 0; w < 4; ++w) { sA += red[w][0]; sB += red[w][1]; }
        const double d = (double)kp;
        const double x = (double)BEVb[b] - (double)BEVa[b]
                       + (double)sB / d - (double)sA / d;
        out[b] = (float)(1.0 / (1.0 + exp(-x)));
    }
}

extern "C" void kernel_launch(void* const* d_in, const int* in_sizes, int n_in,
                              void* d_out, int out_size, void* d_ws, size_t ws_size,
                              hipStream_t stream) {
    (void)in_sizes; (void)n_in; (void)d_ws; (void)ws_size; (void)out_size;
    const float* A    = (const float*)d_in[0];  // outcomeA [16384,4,256] f32
    const float* Bo   = (const float*)d_in[1];  // outcomeB [16384,4,256] f32
    const float* BEVa = (const float*)d_in[2];  // [16384] f32
    const float* BEVb = (const float*)d_in[3];  // [16384] f32
    const int*   kapa = (const int*)d_in[4];    // [16384] int32
    // d_in[5] = batch_size (scalar), d_in[6] = features (dead) — unused
    const float* mean = (const float*)d_in[7];  // [4] f32
    float* out = (float*)d_out;                 // [16384] f32

    bayes_kernel<<<16384, 256, 0, stream>>>(A, Bo, BEVa, BEVb, kapa, mean, out);
}

// Round 8
// 164.184 us; speedup vs baseline: 1.1842x; 1.1842x over previous
//
#include <hip/hip_runtime.h>
#include <stdint.h>
#include <math.h>

// RNG (VERIFIED bit-exact, R7 absmax 0.0): jax partitionable threefry,
//   bits[i] = x0 ^ x1 of threefry2x32(key=[0,42], c0=0, c1=i),
//   u = (bits>>9) * 2^-23 exactly, i = ((b*256+s)*4+k).
// Decision: argmax_k [ (m_k - mx) - log(w_k) ],  w_k = -log(u_k+1e-20)+1e-20
// (monotone-equivalent to the reference's argmax(logits+gumbel); first-wins).
// Two-tier: f32 hw-log fast path with margin 5e-4 (error bound ~1e-5),
// f64 exact fallback on near-ties -> decisions remain bit-exact vs np ref.

__device__ __forceinline__ uint32_t rotl32(uint32_t x, int r) {
    return (x << r) | (x >> (32 - r));   // -> v_alignbit_b32
}

// returns x0 ^ x1 of threefry2x32(key=[0,42], (c0,c1))
__device__ __forceinline__ uint32_t tf2x32_xor(uint32_t c0, uint32_t c1) {
    const uint32_t ks0 = 0u, ks1 = 42u, ks2 = 0x1BD11BF0u; // 0^42^0x1BD11BDA
    uint32_t x0 = c0 + ks0, x1 = c1 + ks1;
#define TF_R(r) { x0 += x1; x1 = rotl32(x1, r); x1 ^= x0; }
    TF_R(13) TF_R(15) TF_R(26) TF_R(6)
    x0 += ks1; x1 += ks2 + 1u;
    TF_R(17) TF_R(29) TF_R(16) TF_R(24)
    x0 += ks2; x1 += ks0 + 2u;
    TF_R(13) TF_R(15) TF_R(26) TF_R(6)
    x0 += ks0; x1 += ks1 + 3u;
    TF_R(17) TF_R(29) TF_R(16) TF_R(24)
    x0 += ks1; x1 += ks2 + 4u;
    TF_R(13) TF_R(15) TF_R(26) TF_R(6)
    x0 += ks2; x1 += ks0 + 5u;
#undef TF_R
    return x0 ^ x1;
}

// fast f32 w = -log(u + 1e-20), accurate in *relative* terms even as u->1
// (series on exact d = 1-u), so log(w) is accurate absolutely everywhere.
__device__ __forceinline__ float fast_w(uint32_t m /* = bits>>9 */) {
    const float u = (float)m * 0x1p-23f;                 // exact
    if (u > 0.96875f) {
        const float d  = (float)(0x800000u - m) * 0x1p-23f;  // 1-u exact
        const float d2 = d * d;
        // -log(1-d) = d + d^2/2 + d^3/3 + d^4/4 + d^5/5, err ~ d^6/6 < 5e-9 rel
        return d + d2 * (0.5f + d * (0.333333333f + d * (0.25f + d * 0.2f)));
    }
    return -__logf(u + 1e-20f);
}

__global__ __launch_bounds__(256) void bayes_kernel(
    const float* __restrict__ A,     // [B,4,S] outcomeA
    const float* __restrict__ Bo,    // [B,4,S] outcomeB
    const float* __restrict__ BEVa,  // [B]
    const float* __restrict__ BEVb,  // [B]
    const int*   __restrict__ kapa,  // [B]
    const float* __restrict__ mean,  // [4]
    float*       __restrict__ out)   // [B]
{
    const int b = blockIdx.x;           // 0..16383
    const int s = threadIdx.x;          // 0..255
    const int kp = kapa[b];             // block-uniform

    int ksel = 0;
    if (s < kp) {                       // masked-out samples never matter
        const float m0 = mean[0], m1 = mean[1], m2 = mean[2], m3 = mean[3];
        const float mx = fmaxf(fmaxf(m0, m1), fmaxf(m2, m3));
        const float c[4] = { m0 - mx, m1 - mx, m2 - mx, m3 - mx };

        const uint32_t i0 = ((uint32_t)(b * 256 + s)) * 4u;
        uint32_t bits[4];
        float sc[4];
#pragma unroll
        for (int k = 0; k < 4; ++k) {
            bits[k] = tf2x32_xor(0u, i0 + (uint32_t)k);
            sc[k]   = c[k] - __logf(fast_w(bits[k] >> 9));
        }

        // argmax (first-wins) + top-2 gap
        float b1 = sc[0], b2 = -3.4e38f;
        ksel = 0;
#pragma unroll
        for (int k = 1; k < 4; ++k) {
            if (sc[k] > b1)      { b2 = b1; b1 = sc[k]; ksel = k; }
            else if (sc[k] > b2) { b2 = sc[k]; }
        }

        if (b1 - b2 < 5e-4f) {
            // exact f64 re-decision (matches np reference incl. true ties)
            double best = -1.0e308;
            ksel = 0;
#pragma unroll
            for (int k = 0; k < 4; ++k) {
                const double u = (double)((float)(bits[k] >> 9) * 0x1p-23f);
                const double w = -log(u + 1e-20) + 1e-20;
                const double sk = ((double)c[k]) - log(w);
                if (sk > best) { best = sk; ksel = k; }   // first-wins
            }
        }
    }

    float av = 0.0f, bv = 0.0f;
    if (s < kp) {
        const int off = (b * 4 + ksel) * 256 + s;
        av = A[off];
        bv = Bo[off];
    }

    // wave (64-lane) reduce, then cross-wave via LDS
#pragma unroll
    for (int off = 32; off >= 1; off >>= 1) {
        av += __shfl_down(av, off);
        bv += __shfl_down(bv, off);
    }

    __shared__ float red[4][2];
    const int wid  = threadIdx.x >> 6;
    const int lane = threadIdx.x & 63;
    if (lane == 0) { red[wid][0] = av; red[wid][1] = bv; }
    __syncthreads();

    if (threadIdx.x == 0) {
        float sA = 0.f, sB = 0.f;
#pragma unroll
        for (int w = 0; w < 4; ++w) { sA += red[w][0]; sB += red[w][1]; }
        const double d = (double)kp;
        const double x = (double)BEVb[b] - (double)BEVa[b]
                       + (double)sB / d - (double)sA / d;
        out[b] = (float)(1.0 / (1.0 + exp(-x)));
    }
}

extern "C" void kernel_launch(void* const* d_in, const int* in_sizes, int n_in,
                              void* d_out, int out_size, void* d_ws, size_t ws_size,
                              hipStream_t stream) {
    (void)in_sizes; (void)n_in; (void)d_ws; (void)ws_size; (void)out_size;
    const float* A    = (const float*)d_in[0];  // outcomeA [16384,4,256] f32
    const float* Bo   = (const float*)d_in[1];  // outcomeB [16384,4,256] f32
    const float* BEVa = (const float*)d_in[2];  // [16384] f32
    const float* BEVb = (const float*)d_in[3];  // [16384] f32
    const int*   kapa = (const int*)d_in[4];    // [16384] int32
    // d_in[5] = batch_size (scalar), d_in[6] = features (dead) — unused
    const float* mean = (const float*)d_in[7];  // [4] f32
    float* out = (float*)d_out;                 // [16384] f32

    bayes_kernel<<<16384, 256, 0, stream>>>(A, Bo, BEVa, BEVb, kapa, mean, out);
}

// Round 9
// 158.747 us; speedup vs baseline: 1.2248x; 1.0343x over previous
//
#include <hip/hip_runtime.h>
#include <stdint.h>
#include <math.h>

// RNG (VERIFIED bit-exact, R7/R8 absmax 0.0): jax partitionable threefry,
//   bits[i] = x0 ^ x1 of threefry2x32(key=[0,42], c0=0, c1=i),
//   u = (bits>>9) * 2^-23 exactly, i = ((b*256+s)*4+k).
// Decision: argmax_k [ c_k - log(w_k) ], c_k = mean_k - max(mean),
//   w_k = -log(u_k + 1e-20) + 1e-20  (monotone-equivalent to reference's
//   argmax(logits+gumbel); first-wins ties = jnp.argmax).
// Key speedup: when c1==c2==c3 (true for mean=[2,1,1,1]), ranking within
// {1,2,3} is EXACTLY the integer argmax of m_k = bits_k>>9 (ref's f64 chain
// is strictly monotone in m; equal m -> identical scores -> first-wins).
// Only the cross-group compare (class 0 vs group winner) needs logs:
// fast f32 with margin 5e-4 (error bound ~5e-6), exact-f64 fallback.
// Layout: ONE WAVE PER ROW (4 rows/block) -> no LDS, no barrier, no idle
// waves; lane L handles s = L + 64j, j=0..3.

__device__ __forceinline__ uint32_t rotl32(uint32_t x, int r) {
    return (x << r) | (x >> (32 - r));   // -> v_alignbit_b32
}

// returns x0 ^ x1 of threefry2x32(key=[0,42], (c0,c1))
__device__ __forceinline__ uint32_t tf2x32_xor(uint32_t c0, uint32_t c1) {
    const uint32_t ks0 = 0u, ks1 = 42u, ks2 = 0x1BD11BF0u; // 0^42^0x1BD11BDA
    uint32_t x0 = c0 + ks0, x1 = c1 + ks1;
#define TF_R(r) { x0 += x1; x1 = rotl32(x1, r); x1 ^= x0; }
    TF_R(13) TF_R(15) TF_R(26) TF_R(6)
    x0 += ks1; x1 += ks2 + 1u;
    TF_R(17) TF_R(29) TF_R(16) TF_R(24)
    x0 += ks2; x1 += ks0 + 2u;
    TF_R(13) TF_R(15) TF_R(26) TF_R(6)
    x0 += ks0; x1 += ks1 + 3u;
    TF_R(17) TF_R(29) TF_R(16) TF_R(24)
    x0 += ks1; x1 += ks2 + 4u;
    TF_R(13) TF_R(15) TF_R(26) TF_R(6)
    x0 += ks2; x1 += ks0 + 5u;
#undef TF_R
    return x0 ^ x1;
}

// fast f32 w = -log(u + 1e-20), relative-accurate even as u->1 (exact-d series)
__device__ __forceinline__ float fast_w(uint32_t m /* = bits>>9 */) {
    const float u  = (float)m * 0x1p-23f;                    // exact
    const float wl = -__logf(u + 1e-20f);
    const float d  = (float)(0x800000u - m) * 0x1p-23f;      // 1-u exact
    const float d2 = d * d;
    const float ws = d + d2 * (0.5f + d * (0.333333333f + d * (0.25f + d * 0.2f)));
    return (u > 0.96875f) ? ws : wl;                         // branchless select
}

// exact f64 log(w) matching the np reference chain
__device__ __forceinline__ double exact_lw(uint32_t m) {
    const double u = (double)m * 0x1p-23;
    const double w = -log(u + 1e-20) + 1e-20;
    return log(w);
}

__global__ __launch_bounds__(256) void bayes_kernel(
    const float* __restrict__ A,     // [B,4,S] outcomeA
    const float* __restrict__ Bo,    // [B,4,S] outcomeB
    const float* __restrict__ BEVa,  // [B]
    const float* __restrict__ BEVb,  // [B]
    const int*   __restrict__ kapa,  // [B]
    const float* __restrict__ mean,  // [4]
    float*       __restrict__ out)   // [B]
{
    const int wid  = threadIdx.x >> 6;
    const int lane = threadIdx.x & 63;
    const int b    = (blockIdx.x << 2) | wid;   // one wave per row
    const int kp   = kapa[b];                   // wave-uniform

    const float m0 = mean[0], m1 = mean[1], m2 = mean[2], m3 = mean[3];
    const float mx = fmaxf(fmaxf(m0, m1), fmaxf(m2, m3));
    const float c0 = m0 - mx, c1 = m1 - mx, c2 = m2 - mx, c3 = m3 - mx;
    const bool grouped = (c1 == c2) && (c2 == c3);   // uniform branch

    const float* __restrict__ Arow = A  + (size_t)b * 1024;
    const float* __restrict__ Brow = Bo + (size_t)b * 1024;

    float av = 0.0f, bv = 0.0f;
#pragma unroll
    for (int j = 0; j < 4; ++j) {
        const int s = lane + (j << 6);
        if (s < kp) {
            const uint32_t i0 = ((uint32_t)(b * 256 + s)) << 2;
            uint32_t m[4];
#pragma unroll
            for (int k = 0; k < 4; ++k)
                m[k] = tf2x32_xor(0u, i0 + (uint32_t)k) >> 9;

            int ksel;
            if (grouped) {
                // exact integer ranking within equal-logit group {1,2,3}
                int jg = 1; uint32_t mm = m[1];
                if (m[2] > mm) { mm = m[2]; jg = 2; }
                if (m[3] > mm) { mm = m[3]; jg = 3; }
                const float s0f = c0 - __logf(fast_w(m[0]));
                const float sjf = c1 - __logf(fast_w(mm));
                ksel = (s0f >= sjf) ? 0 : jg;               // index 0 first-wins
                if (fabsf(s0f - sjf) < 5e-4f) {             // rare exact path
                    const double S0 = (double)c0 - exact_lw(m[0]);
                    const double Sj = (double)c1 - exact_lw(mm);
                    ksel = (S0 >= Sj) ? 0 : jg;
                }
            } else {
                const float cc[4] = { c0, c1, c2, c3 };
                float sc[4];
#pragma unroll
                for (int k = 0; k < 4; ++k)
                    sc[k] = cc[k] - __logf(fast_w(m[k]));
                float b1 = sc[0], b2 = -3.4e38f; ksel = 0;
#pragma unroll
                for (int k = 1; k < 4; ++k) {
                    if (sc[k] > b1)      { b2 = b1; b1 = sc[k]; ksel = k; }
                    else if (sc[k] > b2) { b2 = sc[k]; }
                }
                if (b1 - b2 < 5e-4f) {
                    double best = -1.0e308; ksel = 0;
#pragma unroll
                    for (int k = 0; k < 4; ++k) {
                        const double sk = (double)cc[k] - exact_lw(m[k]);
                        if (sk > best) { best = sk; ksel = k; }
                    }
                }
            }
            const int off = (ksel << 8) + s;
            av += Arow[off];
            bv += Brow[off];
        }
    }

    // wave-level reduce (64 lanes) — no LDS, no barrier
#pragma unroll
    for (int off = 32; off >= 1; off >>= 1) {
        av += __shfl_down(av, off);
        bv += __shfl_down(bv, off);
    }

    if (lane == 0) {
        const double d = (double)kp;
        const double x = (double)BEVb[b] - (double)BEVa[b]
                       + (double)bv / d - (double)av / d;
        out[b] = (float)(1.0 / (1.0 + exp(-x)));
    }
}

extern "C" void kernel_launch(void* const* d_in, const int* in_sizes, int n_in,
                              void* d_out, int out_size, void* d_ws, size_t ws_size,
                              hipStream_t stream) {
    (void)in_sizes; (void)n_in; (void)d_ws; (void)ws_size; (void)out_size;
    const float* A    = (const float*)d_in[0];  // outcomeA [16384,4,256] f32
    const float* Bo   = (const float*)d_in[1];  // outcomeB [16384,4,256] f32
    const float* BEVa = (const float*)d_in[2];  // [16384] f32
    const float* BEVb = (const float*)d_in[3];  // [16384] f32
    const int*   kapa = (const int*)d_in[4];    // [16384] int32
    // d_in[5] = batch_size (scalar), d_in[6] = features (dead) — unused
    const float* mean = (const float*)d_in[7];  // [4] f32
    float* out = (float*)d_out;                 // [16384] f32

    bayes_kernel<<<4096, 256, 0, stream>>>(A, Bo, BEVa, BEVb, kapa, mean, out);
}

// Round 10
// 156.139 us; speedup vs baseline: 1.2452x; 1.0167x over previous
//
#include <hip/hip_runtime.h>
#include <stdint.h>
#include <math.h>

// RNG (VERIFIED bit-exact, R7/R8/R9 absmax 0.0): jax partitionable threefry,
//   bits[i] = x0 ^ x1 of threefry2x32(key=[0,42], c0=0, c1=i),
//   u = (bits>>9) * 2^-23 exactly, i = ((b*256+s)*4+k).
// Decision: argmax_k [ c_k - log(w_k) ], c_k = mean_k - max(mean),
//   w_k = -log(u_k + 1e-20) + 1e-20 (monotone-equivalent to the reference's
//   argmax(logits+gumbel); first-wins ties = jnp.argmax).
// Algebra (mean=[2,1,1,1] => c1==c2==c3):
//   * within equal-logit group {1,2,3}: ranking == integer argmax of
//     m_k = bits_k>>9 (f64 chain strictly monotone in m; equal m -> equal
//     score -> first-wins).  Zero transcendentals.
//   * group-winner vs class 0:  s0 >= sj  <=>  wm >= K*w0,  K = exp(c1-c0)
//     (wave-uniform).  2 transcendentals/sample total (inside fast_w).
//   * relative margin 4e-6 (error bound ~3e-7) -> exact-f64 fallback keeps
//     decisions bit-exact vs the np reference, incl. true ties.
// Mapping (R9 lesson): one THREAD per sample, one block per row — max TLP
// (65536 short waves) hides cipher/log dep-chains; R9's wave-per-row lost
// 30% VALUBusy to serialization.

__device__ __forceinline__ uint32_t rotl32(uint32_t x, int r) {
    return (x << r) | (x >> (32 - r));   // -> v_alignbit_b32
}

// returns x0 ^ x1 of threefry2x32(key=[0,42], (c0,c1))
__device__ __forceinline__ uint32_t tf2x32_xor(uint32_t c0, uint32_t c1) {
    const uint32_t ks0 = 0u, ks1 = 42u, ks2 = 0x1BD11BF0u; // 0^42^0x1BD11BDA
    uint32_t x0 = c0 + ks0, x1 = c1 + ks1;
#define TF_R(r) { x0 += x1; x1 = rotl32(x1, r); x1 ^= x0; }
    TF_R(13) TF_R(15) TF_R(26) TF_R(6)
    x0 += ks1; x1 += ks2 + 1u;
    TF_R(17) TF_R(29) TF_R(16) TF_R(24)
    x0 += ks2; x1 += ks0 + 2u;
    TF_R(13) TF_R(15) TF_R(26) TF_R(6)
    x0 += ks0; x1 += ks1 + 3u;
    TF_R(17) TF_R(29) TF_R(16) TF_R(24)
    x0 += ks1; x1 += ks2 + 4u;
    TF_R(13) TF_R(15) TF_R(26) TF_R(6)
    x0 += ks2; x1 += ks0 + 5u;
#undef TF_R
    return x0 ^ x1;
}

// fast f32 w = -log(u + 1e-20), relative-accurate everywhere (~3e-7):
// hw log for u <= 0.96875, exact-d series for u -> 1.
__device__ __forceinline__ float fast_w(uint32_t m /* = bits>>9 */) {
    const float u  = (float)m * 0x1p-23f;                    // exact
    const float wl = -__logf(u + 1e-20f);
    const float d  = (float)(0x800000u - m) * 0x1p-23f;      // 1-u exact
    const float d2 = d * d;
    const float ws = d + d2 * (0.5f + d * (0.333333333f + d * (0.25f + d * 0.2f)));
    return (u > 0.96875f) ? ws : wl;
}

// exact f64 log(w) matching the np reference chain (validated bit-exact R8)
__device__ __forceinline__ double exact_lw(uint32_t m) {
    const double u = (double)m * 0x1p-23;
    const double w = -log(u + 1e-20) + 1e-20;
    return log(w);
}

__global__ __launch_bounds__(256) void bayes_kernel(
    const float* __restrict__ A,     // [B,4,S] outcomeA
    const float* __restrict__ Bo,    // [B,4,S] outcomeB
    const float* __restrict__ BEVa,  // [B]
    const float* __restrict__ BEVb,  // [B]
    const int*   __restrict__ kapa,  // [B]
    const float* __restrict__ mean,  // [4]
    float*       __restrict__ out)   // [B]
{
    const int b  = blockIdx.x;          // 0..16383, one block per row
    const int s  = threadIdx.x;         // 0..255, one thread per sample
    const int kp = kapa[b];             // block-uniform

    int ksel = 0;
    if (s < kp) {                       // masked-out samples never matter
        const float m0f = mean[0], m1f = mean[1], m2f = mean[2], m3f = mean[3];
        const float mx = fmaxf(fmaxf(m0f, m1f), fmaxf(m2f, m3f));
        const float c0 = m0f - mx, c1 = m1f - mx, c2 = m2f - mx, c3 = m3f - mx;
        const bool grouped = (c1 == c2) && (c2 == c3);   // uniform branch

        const uint32_t i0 = ((uint32_t)(b * 256 + s)) << 2;
        uint32_t m[4];
#pragma unroll
        for (int k = 0; k < 4; ++k)
            m[k] = tf2x32_xor(0u, i0 + (uint32_t)k) >> 9;

        if (grouped) {
            // exact integer ranking within equal-logit group {1,2,3}
            int jg = 1; uint32_t mm = m[1];
            if (m[2] > mm) { mm = m[2]; jg = 2; }
            if (m[3] > mm) { mm = m[3]; jg = 3; }
            // class 0 vs group winner:  s0 >= sj  <=>  wm >= K*w0
            const float K  = __expf(c1 - c0);            // uniform
            const float w0 = fast_w(m[0]);
            const float wm = fast_w(mm);
            const float t  = K * w0;
            ksel = (wm >= t) ? 0 : jg;                   // ties -> index 0
            if (fabsf(wm - t) < 4e-6f * (wm + t)) {      // rare exact path
                const double S0 = (double)c0 - exact_lw(m[0]);
                const double Sj = (double)c1 - exact_lw(mm);
                ksel = (S0 >= Sj) ? 0 : jg;
            }
        } else {
            const float cc[4] = { c0, c1, c2, c3 };
            float sc[4];
#pragma unroll
            for (int k = 0; k < 4; ++k)
                sc[k] = cc[k] - __logf(fast_w(m[k]));
            float b1 = sc[0], b2 = -3.4e38f; ksel = 0;
#pragma unroll
            for (int k = 1; k < 4; ++k) {
                if (sc[k] > b1)      { b2 = b1; b1 = sc[k]; ksel = k; }
                else if (sc[k] > b2) { b2 = sc[k]; }
            }
            if (b1 - b2 < 5e-4f) {
                double best = -1.0e308; ksel = 0;
#pragma unroll
                for (int k = 0; k < 4; ++k) {
                    const double sk = (double)cc[k] - exact_lw(m[k]);
                    if (sk > best) { best = sk; ksel = k; }
                }
            }
        }
    }

    float av = 0.0f, bv = 0.0f;
    if (s < kp) {
        const int off = (b * 4 + ksel) * 256 + s;
        av = A[off];
        bv = Bo[off];
    }

    // wave (64-lane) reduce, then cross-wave via LDS
#pragma unroll
    for (int off = 32; off >= 1; off >>= 1) {
        av += __shfl_down(av, off);
        bv += __shfl_down(bv, off);
    }

    __shared__ float red[4][2];
    const int wid  = threadIdx.x >> 6;
    const int lane = threadIdx.x & 63;
    if (lane == 0) { red[wid][0] = av; red[wid][1] = bv; }
    __syncthreads();

    if (threadIdx.x == 0) {
        float sA = 0.f, sB = 0.f;
#pragma unroll
        for (int w = 0; w < 4; ++w) { sA += red[w][0]; sB += red[w][1]; }
        const double d = (double)kp;
        const double x = (double)BEVb[b] - (double)BEVa[b]
                       + (double)sB / d - (double)sA / d;
        out[b] = (float)(1.0 / (1.0 + exp(-x)));
    }
}

extern "C" void kernel_launch(void* const* d_in, const int* in_sizes, int n_in,
                              void* d_out, int out_size, void* d_ws, size_t ws_size,
                              hipStream_t stream) {
    (void)in_sizes; (void)n_in; (void)d_ws; (void)ws_size; (void)out_size;
    const float* A    = (const float*)d_in[0];  // outcomeA [16384,4,256] f32
    const float* Bo   = (const float*)d_in[1];  // outcomeB [16384,4,256] f32
    const float* BEVa = (const float*)d_in[2];  // [16384] f32
    const float* BEVb = (const float*)d_in[3];  // [16384] f32
    const int*   kapa = (const int*)d_in[4];    // [16384] int32
    // d_in[5] = batch_size (scalar), d_in[6] = features (dead) — unused
    const float* mean = (const float*)d_in[7];  // [4] f32
    float* out = (float*)d_out;                 // [16384] f32

    bayes_kernel<<<16384, 256, 0, stream>>>(A, Bo, BEVa, BEVb, kapa, mean, out);
}